// Round 7
// baseline (190.489 us; speedup 1.0000x reference)
//
#include <hip/hip_runtime.h>

#define GAMMA 12.0f
#define DIM 256
#define NROWS 500
#define CW 64                               // halves per chunk slice (128 B rows)
#define NCHUNK 4                            // DIM / CW
#define ROWS_PAD 504                        // region = 504*128 B = 64512 B
#define REGION_HALVES (ROWS_PAD * CW)       // 32256
#define REGION_BYTES (REGION_HALVES * 2)    // 64512
#define STAGE_ITERS (REGION_BYTES / 1024)   // 63 wave-loads of 1024 B per chunk
#define THREADS 1024
#define WAVES 16
#define PASSES 16
#define TPB 2048                            // triplets per block

typedef _Float16 h2 __attribute__((ext_vector_type(2)));

static __device__ __forceinline__ unsigned short f2h(float x) {
    _Float16 h = (_Float16)x;
    return __builtin_bit_cast(unsigned short, h);
}

// acc += |h + r - t| over one packed f16 pair, f32 accumulate via v_dot2_f32_f16
static __device__ __forceinline__ float acc_pair(unsigned uh, unsigned ur, unsigned ut, float acc) {
    h2 h = __builtin_bit_cast(h2, uh);
    h2 r = __builtin_bit_cast(h2, ur);
    h2 t = __builtin_bit_cast(h2, ut);
    h2 d = (h + r) - t;                                           // v_pk_add_f16 x2
    unsigned ad = __builtin_bit_cast(unsigned, d) & 0x7FFF7FFFu;  // packed abs
    h2 one = { (_Float16)1.0f, (_Float16)1.0f };
    return __builtin_amdgcn_fdot2(__builtin_bit_cast(h2, ad), one, acc, false);
}

// tab16 layout: [table][chunk][ROWS_PAD][CW] halves (rows >= NROWS junk, never read)
__global__ __launch_bounds__(256) void transe_convert(
    const float* __restrict__ node, const float* __restrict__ rel,
    unsigned short* __restrict__ out)
{
    const int per = NROWS * DIM;                 // 128000
    int t8 = (blockIdx.x * 256 + threadIdx.x) * 8;
    if (t8 >= 2 * per) return;
    int table = t8 >= per;
    int e = t8 - table * per;
    const float* src = table ? rel : node;
    float4 f0 = *(const float4*)(src + e);
    float4 f1 = *(const float4*)(src + e + 4);
    int row = e >> 8;
    int d = e & (DIM - 1);
    int c = d >> 6, w = d & (CW - 1);            // w multiple of 8 -> 16B aligned store
    union { unsigned short us[8]; uint4 v; } o;
    o.us[0] = f2h(f0.x); o.us[1] = f2h(f0.y); o.us[2] = f2h(f0.z); o.us[3] = f2h(f0.w);
    o.us[4] = f2h(f1.x); o.us[5] = f2h(f1.y); o.us[6] = f2h(f1.z); o.us[7] = f2h(f1.w);
    *(uint4*)(out + (size_t)(table * NCHUNK + c) * REGION_HALVES + row * CW + w) = o.v;
}

// 8 lanes per triplet, 128 B per row-chunk. h,t from double-buffered node LDS
// (wave ds_read_b128 = 8 rows x 128 B -> every bank exactly 8 words = inherent
// minimum -> conflict-free). r from L2-resident global f16 table, 2-deep prefetch.
// KEY: the stage(c+1) global_load_lds burst is issued AFTER the pass loop, so
// per-pass r-consumes wait vmcnt(<=2) instead of draining the staging queue.
__global__ __launch_bounds__(THREADS) void transe_main(
    const unsigned short* __restrict__ tab16,
    const int* __restrict__ trip,
    const float* __restrict__ node_f32,
    const float* __restrict__ rel_f32,
    float* __restrict__ out, int B)
{
    __shared__ __align__(16) unsigned short lbuf[2 * REGION_HALVES]; // 129024 B
    __shared__ int ltrip[TPB];                                       // 8192 B packed

    const int tid  = threadIdx.x;
    const int wid  = tid >> 6;
    const int lane = tid & 63;
    const int g    = lane >> 3;   // group (triplet) within wave
    const int m    = lane & 7;    // member within group
    const int moff = m * 16;
    const long base = (long)blockIdx.x * TPB;

    const char* srcb = (const char*)tab16;
    char* ldsb = (char*)lbuf;

    // ---- issue chunk-0 node staging into buf0 (async global->LDS) ----
    #pragma unroll 1
    for (int i = wid; i < STAGE_ITERS; i += WAVES) {
        const char* src = srcb + (size_t)i * 1024 + (size_t)lane * 16;
        char* dst = ldsb + i * 1024;
        __builtin_amdgcn_global_load_lds(
            (const __attribute__((address_space(1))) unsigned int*)src,
            (__attribute__((address_space(3))) unsigned int*)dst, 16, 0, 0);
    }

    // ---- pack triplets: h | r<<10 | t<<20 | oob<<30 | invalid<<31 (clamped) ----
    for (int s = tid; s < TPB; s += THREADS) {
        long j = base + s;
        unsigned pk;
        if (j < B) {
            int h = trip[3 * j], r = trip[3 * j + 1], t = trip[3 * j + 2];
            unsigned oob = ((unsigned)h >= NROWS || (unsigned)r >= NROWS || (unsigned)t >= NROWS)
                           ? (1u << 30) : 0u;
            unsigned hc = (unsigned)min(max(h, 0), NROWS - 1);
            unsigned rc = (unsigned)min(max(r, 0), NROWS - 1);
            unsigned tc = (unsigned)min(max(t, 0), NROWS - 1);
            pk = hc | (rc << 10) | (tc << 20) | oob;
        } else pk = 1u << 31;
        ltrip[s] = (int)pk;
    }
    __syncthreads();   // ltrip ready AND chunk-0 staged

    unsigned pidx[PASSES];
    #pragma unroll
    for (int p = 0; p < PASSES; ++p)
        pidx[p] = (unsigned)ltrip[wid * (8 * PASSES) + p * 8 + g];

    float acc[PASSES];
    #pragma unroll
    for (int p = 0; p < PASSES; ++p) acc[p] = 0.f;

    for (int c = 0; c < NCHUNK; ++c) {
        const char* lbase = ldsb + (c & 1) * REGION_BYTES;
        const char* relc  = srcb + (size_t)(NCHUNK + c) * REGION_BYTES;

        // 2-deep r prefetch in two named regs (static ping-pong under full unroll)
        uint4 r0 = *(const uint4*)(relc + (((pidx[0] >> 10) & 1023u) << 7) + moff);
        uint4 r1 = *(const uint4*)(relc + (((pidx[1] >> 10) & 1023u) << 7) + moff);

        #pragma unroll
        for (int p = 0; p < PASSES; ++p) {
            uint4 rv = (p & 1) ? r1 : r0;
            if (p + 2 < PASSES) {
                unsigned pn = pidx[p + 2];
                uint4 rn = *(const uint4*)(relc + (((pn >> 10) & 1023u) << 7) + moff);
                if (p & 1) r1 = rn; else r0 = rn;
            }
            unsigned pk = pidx[p];
            uint4 hv = *(const uint4*)(lbase + ((pk & 1023u) << 7) + moff);
            uint4 tv = *(const uint4*)(lbase + (((pk >> 20) & 1023u) << 7) + moff);
            // two independent dot2 chains
            float a0 = acc[p], a1 = 0.f;
            a0 = acc_pair(hv.x, rv.x, tv.x, a0);
            a1 = acc_pair(hv.y, rv.y, tv.y, a1);
            a0 = acc_pair(hv.z, rv.z, tv.z, a0);
            a1 = acc_pair(hv.w, rv.w, tv.w, a1);
            acc[p] = a0 + a1;
        }

        // stage next chunk AFTER compute: r-consumes above never wait on this burst;
        // the barrier right below drains it (vmcnt 0) exactly once per chunk.
        if (c + 1 < NCHUNK) {
            const char* cb = srcb + (size_t)(c + 1) * REGION_BYTES;
            char* db = ldsb + ((c + 1) & 1) * REGION_BYTES;
            #pragma unroll 1
            for (int i = wid; i < STAGE_ITERS; i += WAVES) {
                __builtin_amdgcn_global_load_lds(
                    (const __attribute__((address_space(1))) unsigned int*)
                        (cb + (size_t)i * 1024 + (size_t)lane * 16),
                    (__attribute__((address_space(3))) unsigned int*)(db + i * 1024),
                    16, 0, 0);
            }
            __syncthreads();   // buf[c&1] reads done everywhere + stage(c+1) landed
        }
    }

    // reduce over the 8 members of each group; member 0 writes
    #pragma unroll
    for (int p = 0; p < PASSES; ++p) {
        float a = acc[p];
        a += __shfl_xor(a, 1, 64);
        a += __shfl_xor(a, 2, 64);
        a += __shfl_xor(a, 4, 64);
        if (m == 0) {
            unsigned pk = pidx[p];
            int slot = wid * (8 * PASSES) + p * 8 + g;
            long j = base + slot;
            if (!(pk >> 30)) {
                out[j] = GAMMA - a;
            } else if (!(pk >> 31)) {   // oob index: exact f32 fallback (never hit here)
                int hh = trip[3 * j], rr = trip[3 * j + 1], tt = trip[3 * j + 2];
                float s = 0.f;
                for (int d = 0; d < DIM; ++d)
                    s += fabsf(node_f32[(size_t)hh * DIM + d] + rel_f32[(size_t)rr * DIM + d]
                             - node_f32[(size_t)tt * DIM + d]);
                out[j] = GAMMA - s;
            }
        }
    }
}

// Round-1 fallback (only if d_ws is too small for the f16 tables)
__global__ __launch_bounds__(256) void transe_direct(
    const float* __restrict__ node_emb,
    const float* __restrict__ rel_emb,
    const int*   __restrict__ triplets,
    float*       __restrict__ out, int B)
{
    const int wave = blockIdx.x * (blockDim.x >> 6) + (threadIdx.x >> 6);
    const int lane = threadIdx.x & 63;
    if (wave >= B) return;
    const int h_idx = triplets[wave * 3 + 0];
    const int r_idx = triplets[wave * 3 + 1];
    const int t_idx = triplets[wave * 3 + 2];
    const float4 h = ((const float4*)(node_emb + (size_t)h_idx * DIM))[lane];
    const float4 r = ((const float4*)(rel_emb  + (size_t)r_idx * DIM))[lane];
    const float4 t = ((const float4*)(node_emb + (size_t)t_idx * DIM))[lane];
    float s = fabsf(h.x + r.x - t.x) + fabsf(h.y + r.y - t.y)
            + fabsf(h.z + r.z - t.z) + fabsf(h.w + r.w - t.w);
    #pragma unroll
    for (int off = 32; off > 0; off >>= 1) s += __shfl_down(s, off, 64);
    if (lane == 0) out[wave] = GAMMA - s;
}

extern "C" void kernel_launch(void* const* d_in, const int* in_sizes, int n_in,
                              void* d_out, int out_size, void* d_ws, size_t ws_size,
                              hipStream_t stream) {
    const float* node_emb = (const float*)d_in[0];
    const float* rel_emb  = (const float*)d_in[1];
    const int*   triplets = (const int*)d_in[2];
    float*       out      = (float*)d_out;
    const int B = out_size;

    const size_t ws_needed = (size_t)2 * NCHUNK * REGION_HALVES * sizeof(unsigned short); // 516096
    if (ws_size < ws_needed) {
        const int grid = (B + 3) / 4;
        transe_direct<<<grid, 256, 0, stream>>>(node_emb, rel_emb, triplets, out, B);
        return;
    }

    unsigned short* tab16 = (unsigned short*)d_ws;

    const int conv_threads = 2 * NROWS * DIM / 8;   // 32000
    transe_convert<<<(conv_threads + 255) / 256, 256, 0, stream>>>(node_emb, rel_emb, tab16);

    const int grid = (B + TPB - 1) / TPB;           // 245 blocks, 1/CU
    transe_main<<<grid, THREADS, 0, stream>>>(tab16, triplets, node_emb, rel_emb, out, B);
}

// Round 8
// 100.273 us; speedup vs baseline: 1.8997x; 1.8997x over previous
//
#include <hip/hip_runtime.h>

#define GAMMA 12.0f
#define DIM 256
#define NROWS 500
#define CW 64                               // halves per chunk slice (128 B rows)
#define NCHUNK 4                            // DIM / CW
#define ROWS_PAD 504                        // region = 504*128 B = 64512 B
#define REGION_HALVES (ROWS_PAD * CW)       // 32256
#define REGION_BYTES (REGION_HALVES * 2)    // 64512
#define STAGE_ITERS (REGION_BYTES / 1024)   // 63 wave-loads of 1024 B per chunk
#define THREADS 1024
#define WAVES 16

// ws layout
#define TAB_BYTES   ((size_t)2 * NCHUNK * REGION_HALVES * 2)   // 516096
#define PACK_OFF    TAB_BYTES

typedef _Float16 h2 __attribute__((ext_vector_type(2)));

static __device__ __forceinline__ unsigned short f2h(float x) {
    _Float16 h = (_Float16)x;
    return __builtin_bit_cast(unsigned short, h);
}

// acc += |h + r - t| over one packed f16 pair, f32 accumulate via v_dot2_f32_f16
static __device__ __forceinline__ float acc_pair(unsigned uh, unsigned ur, unsigned ut, float acc) {
    h2 h = __builtin_bit_cast(h2, uh);
    h2 r = __builtin_bit_cast(h2, ur);
    h2 t = __builtin_bit_cast(h2, ut);
    h2 d = (h + r) - t;                                           // v_pk_add_f16 x2
    unsigned ad = __builtin_bit_cast(unsigned, d) & 0x7FFF7FFFu;  // packed abs
    h2 one = { (_Float16)1.0f, (_Float16)1.0f };
    return __builtin_amdgcn_fdot2(__builtin_bit_cast(h2, ad), one, acc, false);
}

// ---- prep: f16 tables (chunk-major) + packed triplet indices ----
// tab16 layout: [table][chunk][ROWS_PAD][CW] halves. packed: h|r<<10|t<<20|oob<<30|inv<<31
__global__ __launch_bounds__(256) void transe_prep(
    const float* __restrict__ node, const float* __restrict__ rel,
    const int* __restrict__ trip,
    unsigned short* __restrict__ tab16, unsigned* __restrict__ packed,
    int B, int packn)
{
    int t = blockIdx.x * 256 + threadIdx.x;
    const int per = NROWS * DIM;                 // 128000
    if (t < 2 * per / 8) {
        int t8 = t * 8;
        int table = t8 >= per;
        int e = t8 - table * per;
        const float* src = table ? rel : node;
        float4 f0 = *(const float4*)(src + e);
        float4 f1 = *(const float4*)(src + e + 4);
        int row = e >> 8;
        int d = e & (DIM - 1);
        int c = d >> 6, w = d & (CW - 1);
        union { unsigned short us[8]; uint4 v; } o;
        o.us[0] = f2h(f0.x); o.us[1] = f2h(f0.y); o.us[2] = f2h(f0.z); o.us[3] = f2h(f0.w);
        o.us[4] = f2h(f1.x); o.us[5] = f2h(f1.y); o.us[6] = f2h(f1.z); o.us[7] = f2h(f1.w);
        *(uint4*)(tab16 + (size_t)(table * NCHUNK + c) * REGION_HALVES + row * CW + w) = o.v;
    }
    if (t < packn) {
        unsigned pk;
        if (t < B) {
            int h = trip[3 * (long)t], r = trip[3 * (long)t + 1], tt = trip[3 * (long)t + 2];
            unsigned oob = ((unsigned)h >= NROWS || (unsigned)r >= NROWS || (unsigned)tt >= NROWS)
                           ? (1u << 30) : 0u;
            unsigned hc = (unsigned)min(max(h, 0), NROWS - 1);
            unsigned rc = (unsigned)min(max(r, 0), NROWS - 1);
            unsigned tc = (unsigned)min(max(tt, 0), NROWS - 1);
            pk = hc | (rc << 10) | (tc << 20) | oob;
        } else pk = 1u << 31;
        packed[t] = pk;
    }
}

// ---- main: one chunk per block, no restaging, 2 blocks/CU (8 waves/SIMD) ----
// 8 lanes per triplet, 128 B per row-chunk. h,t from the single staged node
// chunk in LDS (wave ds_read_b128 = 8 rows x 128 B -> conflict-free). r from
// the L2-resident global f16 rel chunk, 1-deep prefetch. Writes per-chunk
// partial sums; combine kernel finishes.
__global__ __launch_bounds__(THREADS, 8) void transe_main2(
    const unsigned short* __restrict__ tab16,
    const unsigned* __restrict__ packed,
    float* __restrict__ partials,
    int B, int ntiles)
{
    __shared__ __align__(16) unsigned short lbuf[REGION_HALVES]; // 64512 B
    __shared__ int ltrip[THREADS];                               // 4096 B

    const int tid  = threadIdx.x;
    const int wid  = tid >> 6;
    const int lane = tid & 63;
    const int g    = lane >> 3;   // group (triplet) within wave
    const int m    = lane & 7;    // member within group
    const int moff = m * 16;

    const int c    = blockIdx.x / ntiles;          // chunk id (slow dim: L2 locality)
    const int tile = blockIdx.x - c * ntiles;
    const int base = tile * THREADS;

    const char* srcb = (const char*)tab16;
    char* ldsb = (char*)lbuf;

    // stage node chunk c (async global->LDS, wave-uniform dest + lane*16)
    const char* cb = srcb + (size_t)c * REGION_BYTES;
    #pragma unroll 1
    for (int i = wid; i < STAGE_ITERS; i += WAVES) {
        __builtin_amdgcn_global_load_lds(
            (const __attribute__((address_space(1))) unsigned int*)
                (cb + (size_t)i * 1024 + (size_t)lane * 16),
            (__attribute__((address_space(3))) unsigned int*)(ldsb + i * 1024),
            16, 0, 0);
    }
    ltrip[tid] = (int)packed[base + tid];
    __syncthreads();   // staging + ltrip done

    unsigned pidx[8];
    #pragma unroll
    for (int p = 0; p < 8; ++p)
        pidx[p] = (unsigned)ltrip[wid * 64 + p * 8 + g];

    const char* relc = srcb + (size_t)(NCHUNK + c) * REGION_BYTES;

    float acc[8];
    #pragma unroll
    for (int p = 0; p < 8; ++p) acc[p] = 0.f;

    uint4 rnext = *(const uint4*)(relc + (((pidx[0] >> 10) & 1023u) << 7) + moff);
    #pragma unroll
    for (int p = 0; p < 8; ++p) {
        uint4 rv = rnext;
        if (p + 1 < 8)
            rnext = *(const uint4*)(relc + (((pidx[p + 1] >> 10) & 1023u) << 7) + moff);
        unsigned pk = pidx[p];
        uint4 hv = *(const uint4*)(ldsb + ((pk & 1023u) << 7) + moff);
        uint4 tv = *(const uint4*)(ldsb + (((pk >> 20) & 1023u) << 7) + moff);
        float a0 = acc[p], a1 = 0.f;
        a0 = acc_pair(hv.x, rv.x, tv.x, a0);
        a1 = acc_pair(hv.y, rv.y, tv.y, a1);
        a0 = acc_pair(hv.z, rv.z, tv.z, a0);
        a1 = acc_pair(hv.w, rv.w, tv.w, a1);
        acc[p] = a0 + a1;
    }

    #pragma unroll
    for (int p = 0; p < 8; ++p) {
        float a = acc[p];
        a += __shfl_xor(a, 1, 64);
        a += __shfl_xor(a, 2, 64);
        a += __shfl_xor(a, 4, 64);
        if (m == 0) {
            int j = base + wid * 64 + p * 8 + g;
            if (j < B) partials[(size_t)c * B + j] = a;
        }
    }
}

// ---- combine: out = GAMMA - sum of 4 chunk partials (oob -> exact f32) ----
__global__ __launch_bounds__(256) void transe_combine(
    const float* __restrict__ partials,
    const unsigned* __restrict__ packed,
    const int* __restrict__ trip,
    const float* __restrict__ node_f32,
    const float* __restrict__ rel_f32,
    float* __restrict__ out, int B)
{
    int j = blockIdx.x * 256 + threadIdx.x;
    if (j >= B) return;
    unsigned pk = packed[j];
    if (!(pk & (1u << 30))) {
        float s = partials[j] + partials[(size_t)B + j]
                + partials[2 * (size_t)B + j] + partials[3 * (size_t)B + j];
        out[j] = GAMMA - s;
    } else {   // oob index: exact f32 fallback (never hit with this generator)
        int hh = trip[3 * (long)j], rr = trip[3 * (long)j + 1], tt = trip[3 * (long)j + 2];
        float s = 0.f;
        for (int d = 0; d < DIM; ++d)
            s += fabsf(node_f32[(size_t)hh * DIM + d] + rel_f32[(size_t)rr * DIM + d]
                     - node_f32[(size_t)tt * DIM + d]);
        out[j] = GAMMA - s;
    }
}

// ---- R5 fallback path (28.7 us) if ws is too small for partials ----
__global__ __launch_bounds__(256) void transe_convert(
    const float* __restrict__ node, const float* __restrict__ rel,
    unsigned short* __restrict__ out)
{
    const int per = NROWS * DIM;
    int t8 = (blockIdx.x * 256 + threadIdx.x) * 8;
    if (t8 >= 2 * per) return;
    int table = t8 >= per;
    int e = t8 - table * per;
    const float* src = table ? rel : node;
    float4 f0 = *(const float4*)(src + e);
    float4 f1 = *(const float4*)(src + e + 4);
    int row = e >> 8;
    int d = e & (DIM - 1);
    int c = d >> 6, w = d & (CW - 1);
    union { unsigned short us[8]; uint4 v; } o;
    o.us[0] = f2h(f0.x); o.us[1] = f2h(f0.y); o.us[2] = f2h(f0.z); o.us[3] = f2h(f0.w);
    o.us[4] = f2h(f1.x); o.us[5] = f2h(f1.y); o.us[6] = f2h(f1.z); o.us[7] = f2h(f1.w);
    *(uint4*)(out + (size_t)(table * NCHUNK + c) * REGION_HALVES + row * CW + w) = o.v;
}

__global__ __launch_bounds__(THREADS) void transe_main_r5(
    const unsigned short* __restrict__ tab16,
    const int* __restrict__ trip,
    const float* __restrict__ node_f32,
    const float* __restrict__ rel_f32,
    float* __restrict__ out, int B)
{
    __shared__ __align__(16) unsigned short lbuf[2 * REGION_HALVES];
    __shared__ int ltrip[2048];
    const int tid  = threadIdx.x;
    const int wid  = tid >> 6;
    const int lane = tid & 63;
    const int g    = lane >> 3;
    const int m    = lane & 7;
    const int moff = m * 16;
    const long base = (long)blockIdx.x * 2048;
    const char* srcb = (const char*)tab16;
    char* ldsb = (char*)lbuf;

    #pragma unroll 1
    for (int i = wid; i < STAGE_ITERS; i += WAVES) {
        __builtin_amdgcn_global_load_lds(
            (const __attribute__((address_space(1))) unsigned int*)
                (srcb + (size_t)i * 1024 + (size_t)lane * 16),
            (__attribute__((address_space(3))) unsigned int*)(ldsb + i * 1024), 16, 0, 0);
    }
    for (int s = tid; s < 2048; s += THREADS) {
        long j = base + s;
        unsigned pk;
        if (j < B) {
            int h = trip[3 * j], r = trip[3 * j + 1], t = trip[3 * j + 2];
            unsigned oob = ((unsigned)h >= NROWS || (unsigned)r >= NROWS || (unsigned)t >= NROWS)
                           ? (1u << 30) : 0u;
            pk = (unsigned)min(max(h, 0), NROWS - 1) | ((unsigned)min(max(r, 0), NROWS - 1) << 10)
               | ((unsigned)min(max(t, 0), NROWS - 1) << 20) | oob;
        } else pk = 1u << 31;
        ltrip[s] = (int)pk;
    }
    __syncthreads();

    unsigned pidx[16];
    #pragma unroll
    for (int p = 0; p < 16; ++p) pidx[p] = (unsigned)ltrip[wid * 128 + p * 8 + g];
    float acc[16];
    #pragma unroll
    for (int p = 0; p < 16; ++p) acc[p] = 0.f;

    for (int c = 0; c < NCHUNK; ++c) {
        const char* lbase = ldsb + (c & 1) * REGION_BYTES;
        const char* relc  = srcb + (size_t)(NCHUNK + c) * REGION_BYTES;
        if (c + 1 < NCHUNK) {
            const char* cb = srcb + (size_t)(c + 1) * REGION_BYTES;
            char* db = ldsb + ((c + 1) & 1) * REGION_BYTES;
            #pragma unroll 1
            for (int i = wid; i < STAGE_ITERS; i += WAVES) {
                __builtin_amdgcn_global_load_lds(
                    (const __attribute__((address_space(1))) unsigned int*)
                        (cb + (size_t)i * 1024 + (size_t)lane * 16),
                    (__attribute__((address_space(3))) unsigned int*)(db + i * 1024), 16, 0, 0);
            }
        }
        uint4 rnext = *(const uint4*)(relc + (((pidx[0] >> 10) & 1023u) << 7) + moff);
        #pragma unroll
        for (int p = 0; p < 16; ++p) {
            uint4 rv = rnext;
            if (p + 1 < 16)
                rnext = *(const uint4*)(relc + (((pidx[p + 1] >> 10) & 1023u) << 7) + moff);
            unsigned pk = pidx[p];
            uint4 hv = *(const uint4*)(lbase + ((pk & 1023u) << 7) + moff);
            uint4 tv = *(const uint4*)(lbase + (((pk >> 20) & 1023u) << 7) + moff);
            float a0 = acc[p], a1 = 0.f;
            a0 = acc_pair(hv.x, rv.x, tv.x, a0);
            a1 = acc_pair(hv.y, rv.y, tv.y, a1);
            a0 = acc_pair(hv.z, rv.z, tv.z, a0);
            a1 = acc_pair(hv.w, rv.w, tv.w, a1);
            acc[p] = a0 + a1;
        }
        __syncthreads();
    }

    #pragma unroll
    for (int p = 0; p < 16; ++p) {
        float a = acc[p];
        a += __shfl_xor(a, 1, 64);
        a += __shfl_xor(a, 2, 64);
        a += __shfl_xor(a, 4, 64);
        if (m == 0) {
            unsigned pk = pidx[p];
            long j = base + wid * 128 + p * 8 + g;
            if (j < B && !(pk >> 30)) out[j] = GAMMA - a;
            else if (j < B && !(pk >> 31)) {
                int hh = trip[3 * j], rr = trip[3 * j + 1], tt = trip[3 * j + 2];
                float s = 0.f;
                for (int d = 0; d < DIM; ++d)
                    s += fabsf(node_f32[(size_t)hh * DIM + d] + rel_f32[(size_t)rr * DIM + d]
                             - node_f32[(size_t)tt * DIM + d]);
                out[j] = GAMMA - s;
            }
        }
    }
}

__global__ __launch_bounds__(256) void transe_direct(
    const float* __restrict__ node_emb,
    const float* __restrict__ rel_emb,
    const int*   __restrict__ triplets,
    float*       __restrict__ out, int B)
{
    const int wave = blockIdx.x * (blockDim.x >> 6) + (threadIdx.x >> 6);
    const int lane = threadIdx.x & 63;
    if (wave >= B) return;
    const int h_idx = triplets[wave * 3 + 0];
    const int r_idx = triplets[wave * 3 + 1];
    const int t_idx = triplets[wave * 3 + 2];
    const float4 h = ((const float4*)(node_emb + (size_t)h_idx * DIM))[lane];
    const float4 r = ((const float4*)(rel_emb  + (size_t)r_idx * DIM))[lane];
    const float4 t = ((const float4*)(node_emb + (size_t)t_idx * DIM))[lane];
    float s = fabsf(h.x + r.x - t.x) + fabsf(h.y + r.y - t.y)
            + fabsf(h.z + r.z - t.z) + fabsf(h.w + r.w - t.w);
    #pragma unroll
    for (int off = 32; off > 0; off >>= 1) s += __shfl_down(s, off, 64);
    if (lane == 0) out[wave] = GAMMA - s;
}

extern "C" void kernel_launch(void* const* d_in, const int* in_sizes, int n_in,
                              void* d_out, int out_size, void* d_ws, size_t ws_size,
                              hipStream_t stream) {
    const float* node_emb = (const float*)d_in[0];
    const float* rel_emb  = (const float*)d_in[1];
    const int*   triplets = (const int*)d_in[2];
    float*       out      = (float*)d_out;
    const int B = out_size;

    const int ntiles = (B + THREADS - 1) / THREADS;      // 489
    const int packn  = ntiles * THREADS;                 // 500736
    const size_t pack_bytes = (size_t)packn * 4;
    const size_t part_off   = PACK_OFF + pack_bytes;     // 16B-aligned
    const size_t ws_needed  = part_off + (size_t)NCHUNK * B * 4;

    if (ws_size >= ws_needed) {
        unsigned short* tab16 = (unsigned short*)d_ws;
        unsigned* packed = (unsigned*)((char*)d_ws + PACK_OFF);
        float* partials  = (float*)((char*)d_ws + part_off);

        transe_prep<<<(packn + 255) / 256, 256, 0, stream>>>(
            node_emb, rel_emb, triplets, tab16, packed, B, packn);
        transe_main2<<<NCHUNK * ntiles, THREADS, 0, stream>>>(
            tab16, packed, partials, B, ntiles);
        transe_combine<<<(B + 255) / 256, 256, 0, stream>>>(
            partials, packed, triplets, node_emb, rel_emb, out, B);
    } else if (ws_size >= TAB_BYTES) {
        unsigned short* tab16 = (unsigned short*)d_ws;
        transe_convert<<<(2 * NROWS * DIM / 8 + 255) / 256, 256, 0, stream>>>(
            node_emb, rel_emb, tab16);
        transe_main_r5<<<(B + 2047) / 2048, THREADS, 0, stream>>>(
            tab16, triplets, node_emb, rel_emb, out, B);
    } else {
        transe_direct<<<(B + 3) / 4, 256, 0, stream>>>(node_emb, rel_emb, triplets, out, B);
    }
}

// Round 9
// 34.323 us; speedup vs baseline: 5.5498x; 2.9214x over previous
//
#include <hip/hip_runtime.h>

#define GAMMA 12.0f
#define DIM 256
#define NROWS 500
#define ROWS_PAD 512
#define SC_BYTES (ROWS_PAD * 128)   // 65536 B: one table's super-chunk (128 fp8 elems x 512 rows)
#define NSC 2                       // 2 super-chunks of 128 elems = DIM
#define THREADS 1024
#define WAVES 16
#define PASSES 16                   // per SC: 2048 triplets / (16 waves * 8 groups)
#define TPB 2048
#define TAB8_BYTES ((size_t)2 * NSC * SC_BYTES)   // 262144

typedef float f32x2 __attribute__((ext_vector_type(2)));

// |h + r - t| over 4 fp8 elems (one 32-bit word per stream), f32 math via pk ops
static __device__ __forceinline__ f32x2 acc_word(unsigned hw, unsigned rw, unsigned tw, f32x2 a) {
    f32x2 h0 = __builtin_amdgcn_cvt_pk_f32_fp8((int)hw, false);
    f32x2 h1 = __builtin_amdgcn_cvt_pk_f32_fp8((int)hw, true);
    f32x2 r0 = __builtin_amdgcn_cvt_pk_f32_fp8((int)rw, false);
    f32x2 r1 = __builtin_amdgcn_cvt_pk_f32_fp8((int)rw, true);
    f32x2 t0 = __builtin_amdgcn_cvt_pk_f32_fp8((int)tw, false);
    f32x2 t1 = __builtin_amdgcn_cvt_pk_f32_fp8((int)tw, true);
    f32x2 d0 = (h0 + r0) - t0;
    f32x2 d1 = (h1 + r1) - t1;
    a.x += __builtin_fabsf(d0.x);  a.y += __builtin_fabsf(d0.y);
    a.x += __builtin_fabsf(d1.x);  a.y += __builtin_fabsf(d1.y);
    return a;
}

// tab8 layout: [table][sc][row<ROWS_PAD][128 B]; elem = sc*128 + byte. Rows >= NROWS junk.
__global__ __launch_bounds__(256) void transe_prep8(
    const float* __restrict__ node, const float* __restrict__ rel,
    unsigned char* __restrict__ tab8)
{
    int t = blockIdx.x * 256 + threadIdx.x;
    const int per = NROWS * DIM;            // 128000
    int t8 = t * 8;
    if (t8 >= 2 * per) return;
    int table = t8 >= per;
    int e = t8 - table * per;
    const float* src = table ? rel : node;
    float4 f0 = *(const float4*)(src + e);
    float4 f1 = *(const float4*)(src + e + 4);
    int row = e >> 8;
    int d = e & (DIM - 1);
    int s = d >> 7, k = d & 127;            // k multiple of 8 -> 8B-aligned store
    int w0 = 0, w1 = 0;
    w0 = __builtin_amdgcn_cvt_pk_fp8_f32(f0.x, f0.y, w0, false);
    w0 = __builtin_amdgcn_cvt_pk_fp8_f32(f0.z, f0.w, w0, true);
    w1 = __builtin_amdgcn_cvt_pk_fp8_f32(f1.x, f1.y, w1, false);
    w1 = __builtin_amdgcn_cvt_pk_fp8_f32(f1.z, f1.w, w1, true);
    *(uint2*)(tab8 + (size_t)(table * NSC + s) * SC_BYTES + row * 128 + k) =
        make_uint2((unsigned)w0, (unsigned)w1);
}

// R5 skeleton, fp8 storage: BOTH tables' current super-chunk live in LDS
// (node 64K + rel 64K). 8 lanes per triplet, 16 B per lane per stream ->
// wave ds_read_b128 = 8 rows x 128 consecutive B -> every bank hit exactly 8x,
// zero conflicts. Inner loop touches ONLY LDS - no L2 latency leg at all.
__global__ __launch_bounds__(THREADS, 4) void transe_main8(
    const unsigned char* __restrict__ tab8,
    const int* __restrict__ trip,
    const float* __restrict__ node_f32,
    const float* __restrict__ rel_f32,
    float* __restrict__ out, int B)
{
    __shared__ __align__(16) unsigned char ltab[2 * SC_BYTES];  // 131072 B
    __shared__ int ltrip[TPB];                                  // 8192 B

    const int tid  = threadIdx.x;
    const int wid  = tid >> 6;
    const int lane = tid & 63;
    const int g    = lane >> 3;   // group (triplet) within wave
    const int m    = lane & 7;    // member within group
    const int moff = m * 16;
    const long base = (long)blockIdx.x * TPB;

    const char* srcb = (const char*)tab8;
    char* ldsb = (char*)ltab;

    // ---- stage SC0 (node + rel regions, async global->LDS, linear dest) ----
    #pragma unroll 1
    for (int i = wid; i < 128; i += WAVES) {
        int region = i >> 6;                 // 0 = node, 1 = rel
        int k = i & 63;
        const char* src = srcb + (size_t)(region * NSC + 0) * SC_BYTES
                        + (size_t)k * 1024 + (size_t)lane * 16;
        char* dst = ldsb + region * SC_BYTES + k * 1024;
        __builtin_amdgcn_global_load_lds(
            (const __attribute__((address_space(1))) unsigned int*)src,
            (__attribute__((address_space(3))) unsigned int*)dst, 16, 0, 0);
    }

    // ---- pack triplets: h | r<<10 | t<<20 | oob<<30 | invalid<<31 (clamped) ----
    for (int s = tid; s < TPB; s += THREADS) {
        long j = base + s;
        unsigned pk;
        if (j < B) {
            int h = trip[3 * j], r = trip[3 * j + 1], t = trip[3 * j + 2];
            unsigned oob = ((unsigned)h >= NROWS || (unsigned)r >= NROWS || (unsigned)t >= NROWS)
                           ? (1u << 30) : 0u;
            unsigned hc = (unsigned)min(max(h, 0), NROWS - 1);
            unsigned rc = (unsigned)min(max(r, 0), NROWS - 1);
            unsigned tc = (unsigned)min(max(t, 0), NROWS - 1);
            pk = hc | (rc << 10) | (tc << 20) | oob;
        } else pk = 1u << 31;
        ltrip[s] = (int)pk;
    }
    __syncthreads();   // SC0 staged + ltrip ready

    unsigned pidx[PASSES];
    #pragma unroll
    for (int p = 0; p < PASSES; ++p)
        pidx[p] = (unsigned)ltrip[wid * (8 * PASSES) + p * 8 + g];

    float acc[PASSES];
    #pragma unroll
    for (int p = 0; p < PASSES; ++p) acc[p] = 0.f;

    for (int sc = 0; sc < NSC; ++sc) {
        if (sc) {
            __syncthreads();   // SC0 compute done everywhere
            #pragma unroll 1
            for (int i = wid; i < 128; i += WAVES) {
                int region = i >> 6;
                int k = i & 63;
                const char* src = srcb + (size_t)(region * NSC + sc) * SC_BYTES
                                + (size_t)k * 1024 + (size_t)lane * 16;
                char* dst = ldsb + region * SC_BYTES + k * 1024;
                __builtin_amdgcn_global_load_lds(
                    (const __attribute__((address_space(1))) unsigned int*)src,
                    (__attribute__((address_space(3))) unsigned int*)dst, 16, 0, 0);
            }
            __syncthreads();   // SC1 staged
        }

        #pragma unroll
        for (int p = 0; p < PASSES; ++p) {
            unsigned pk = pidx[p];
            const uint4 hv = *(const uint4*)(ldsb + ((pk & 1023u) << 7) + moff);
            const uint4 rv = *(const uint4*)(ldsb + SC_BYTES + (((pk >> 10) & 1023u) << 7) + moff);
            const uint4 tv = *(const uint4*)(ldsb + ((pk >> 20 & 1023u) << 7) + moff);
            f32x2 a2 = {0.f, 0.f};
            a2 = acc_word(hv.x, rv.x, tv.x, a2);
            a2 = acc_word(hv.y, rv.y, tv.y, a2);
            a2 = acc_word(hv.z, rv.z, tv.z, a2);
            a2 = acc_word(hv.w, rv.w, tv.w, a2);
            acc[p] += a2.x + a2.y;
        }
    }

    // reduce over the 8 members of each group; member 0 writes
    #pragma unroll
    for (int p = 0; p < PASSES; ++p) {
        float a = acc[p];
        a += __shfl_xor(a, 1, 64);
        a += __shfl_xor(a, 2, 64);
        a += __shfl_xor(a, 4, 64);
        if (m == 0) {
            unsigned pk = pidx[p];
            int slot = wid * (8 * PASSES) + p * 8 + g;
            long j = base + slot;
            if (!(pk >> 30)) {
                out[j] = GAMMA - a;
            } else if (!(pk >> 31)) {   // oob index: exact f32 fallback (never hit here)
                int hh = trip[3 * j], rr = trip[3 * j + 1], tt = trip[3 * j + 2];
                float s = 0.f;
                for (int d = 0; d < DIM; ++d)
                    s += fabsf(node_f32[(size_t)hh * DIM + d] + rel_f32[(size_t)rr * DIM + d]
                             - node_f32[(size_t)tt * DIM + d]);
                out[j] = GAMMA - s;
            }
        }
    }
}

// Fallback (only if ws is too small for the fp8 tables)
__global__ __launch_bounds__(256) void transe_direct(
    const float* __restrict__ node_emb,
    const float* __restrict__ rel_emb,
    const int*   __restrict__ triplets,
    float*       __restrict__ out, int B)
{
    const int wave = blockIdx.x * (blockDim.x >> 6) + (threadIdx.x >> 6);
    const int lane = threadIdx.x & 63;
    if (wave >= B) return;
    const int h_idx = triplets[wave * 3 + 0];
    const int r_idx = triplets[wave * 3 + 1];
    const int t_idx = triplets[wave * 3 + 2];
    const float4 h = ((const float4*)(node_emb + (size_t)h_idx * DIM))[lane];
    const float4 r = ((const float4*)(rel_emb  + (size_t)r_idx * DIM))[lane];
    const float4 t = ((const float4*)(node_emb + (size_t)t_idx * DIM))[lane];
    float s = fabsf(h.x + r.x - t.x) + fabsf(h.y + r.y - t.y)
            + fabsf(h.z + r.z - t.z) + fabsf(h.w + r.w - t.w);
    #pragma unroll
    for (int off = 32; off > 0; off >>= 1) s += __shfl_down(s, off, 64);
    if (lane == 0) out[wave] = GAMMA - s;
}

extern "C" void kernel_launch(void* const* d_in, const int* in_sizes, int n_in,
                              void* d_out, int out_size, void* d_ws, size_t ws_size,
                              hipStream_t stream) {
    const float* node_emb = (const float*)d_in[0];
    const float* rel_emb  = (const float*)d_in[1];
    const int*   triplets = (const int*)d_in[2];
    float*       out      = (float*)d_out;
    const int B = out_size;

    if (ws_size < TAB8_BYTES) {
        transe_direct<<<(B + 3) / 4, 256, 0, stream>>>(node_emb, rel_emb, triplets, out, B);
        return;
    }

    unsigned char* tab8 = (unsigned char*)d_ws;

    const int conv_threads = 2 * NROWS * DIM / 8;   // 32000
    transe_prep8<<<(conv_threads + 255) / 256, 256, 0, stream>>>(node_emb, rel_emb, tab8);

    const int grid = (B + TPB - 1) / TPB;           // 245 blocks, 1/CU
    transe_main8<<<grid, THREADS, 0, stream>>>(tab8, triplets, node_emb, rel_emb, out, B);
}